// Round 1
// baseline (144.806 us; speedup 1.0000x reference)
//
#include <hip/hip_runtime.h>
#include <math.h>

// Problem geometry (fixed by the reference): shape (B=2, T=20, H=480, W=480)
#define TS   20
#define NL   5
#define NS   26            // per-timestep sums: hits[5], p_tot[5], t_tot[5], mae_num[5], cnt, Sp, St, Spt, Spp, Stt
#define HW4C 57600         // 480*480/4 float4 per (b,t) slab

// acc layout: [0..4]=hits, [5..9]=p_tot, [10..14]=t_tot, [15..19]=mae_num,
//             [20]=cnt, [21]=Sp, [22]=St, [23]=Spt, [24]=Spp, [25]=Stt
__device__ __forceinline__ void accum_pixel(float pn, float tn, float mn, float* a)
{
    constexpr float LF = 3.4339872044851463f;  // ln(30+1)
    float p = fmaxf(expf(pn * LF) - 1.0f, 0.0f);
    float q = fmaxf(expf(tn * LF) - 1.0f, 0.0f);
    if (mn > 0.5f) {
        // masked correlation excludes double-zero pixels (< thr[0] both)
        if (!((p < 0.1f) && (q < 0.1f))) {
            a[20] += 1.0f;
            a[21] += p;  a[22] += q;
            a[23] += p * q;  a[24] += p * p;  a[25] += q * q;
        }
        float ad = fabsf(p - q);
        bool p1 = p >= 0.1f, p2 = p >= 1.0f, p3 = p >= 2.0f, p4 = p >= 5.0f, p5 = p >= 8.0f;
        bool q1 = q >= 0.1f, q2 = q >= 1.0f, q3 = q >= 2.0f, q4 = q >= 5.0f, q5 = q >= 8.0f;
        bool pin[NL] = { p1 && !p2, p2 && !p3, p3 && !p4, p4 && !p5, p5 };
        bool qin[NL] = { q1 && !q2, q2 && !q3, q3 && !q4, q4 && !q5, q5 };
        #pragma unroll
        for (int l = 0; l < NL; ++l) {
            if (pin[l])           a[5 + l]  += 1.0f;
            if (qin[l])         { a[10 + l] += 1.0f;  a[15 + l] += ad; }
            if (pin[l] && qin[l]) a[l]      += 1.0f;
        }
    }
}

__global__ __launch_bounds__(256) void metscore_pass1(
    const float4* __restrict__ pred, const float4* __restrict__ targ,
    const float4* __restrict__ mask, float* __restrict__ sums /* [TS][NS] */)
{
    const int t = blockIdx.y;
    const int b = blockIdx.z;
    const size_t base = ((size_t)b * TS + t) * (size_t)HW4C;

    float acc[NS];
    #pragma unroll
    for (int k = 0; k < NS; ++k) acc[k] = 0.0f;

    const int stride = gridDim.x * blockDim.x;
    for (int i = blockIdx.x * blockDim.x + threadIdx.x; i < HW4C; i += stride) {
        float4 pv = pred[base + i];
        float4 tv = targ[base + i];
        float4 mv = mask[base + i];
        accum_pixel(pv.x, tv.x, mv.x, acc);
        accum_pixel(pv.y, tv.y, mv.y, acc);
        accum_pixel(pv.z, tv.z, mv.z, acc);
        accum_pixel(pv.w, tv.w, mv.w, acc);
    }

    // wave(64) shuffle reduce each of the 26 accumulators
    #pragma unroll
    for (int k = 0; k < NS; ++k) {
        float v = acc[k];
        v += __shfl_down(v, 32);
        v += __shfl_down(v, 16);
        v += __shfl_down(v, 8);
        v += __shfl_down(v, 4);
        v += __shfl_down(v, 2);
        v += __shfl_down(v, 1);
        acc[k] = v;
    }

    __shared__ float lds[4][NS];
    const int lane = threadIdx.x & 63;
    const int wv   = threadIdx.x >> 6;
    if (lane == 0) {
        #pragma unroll
        for (int k = 0; k < NS; ++k) lds[wv][k] = acc[k];
    }
    __syncthreads();
    if (threadIdx.x < NS) {
        float s = lds[0][threadIdx.x] + lds[1][threadIdx.x]
                + lds[2][threadIdx.x] + lds[3][threadIdx.x];
        atomicAdd(&sums[t * NS + threadIdx.x], s);
    }
}

// out layout (return order, flat):
// [0]=total, [1..20]=score_time, [21..40]=r_time, [41..140]=ts_mat[t][l],
// [141..240]=mae_mat[t][l], [241..245]=ts_mat.mean(0), [246..250]=mae_mat.mean(0)
__global__ __launch_bounds__(128) void metscore_final(
    const float* __restrict__ sums, float* __restrict__ out)
{
    __shared__ float ts_s[TS][NL];
    __shared__ float mae_s[TS][NL];
    __shared__ float sc_s[TS];

    const int tid = threadIdx.x;

    if (tid < TS * NL) {
        int t = tid / NL, l = tid % NL;
        const float* s = sums + t * NS;
        float h = s[l], pt = s[5 + l], tt = s[10 + l], mn = s[15 + l];
        float ts  = h / (pt + tt - h + 1e-8f);
        float mae = (tt > 0.0f) ? (mn / fmaxf(tt, 1.0f)) : 0.0f;
        ts_s[t][l]  = ts;
        mae_s[t][l] = mae;
        out[41 + tid]  = ts;
        out[141 + tid] = mae;
    }
    __syncthreads();

    if (tid < TS) {
        const float* s = sums + tid * NS;
        double cnt = s[20], sp = s[21], st = s[22];
        double spt = s[23], spp = s[24], stt = s[25];
        double sc = fmax(cnt, 1.0);
        double pm = sp / sc, tm = st / sc;
        double num = spt - pm * st - tm * sp + pm * tm * cnt;
        double vp  = spp - 2.0 * pm * sp + pm * pm * cnt;
        double vt  = stt - 2.0 * tm * st + tm * tm * cnt;
        double den = sqrt(vp * vt);
        double r = num / (den + 1e-6);
        r = fmin(fmax(r, -1.0), 1.0);
        float rt = (cnt > 0.0) ? (float)r : 0.0f;
        out[21 + tid] = rt;

        const float LW[NL] = {0.1f, 0.1f, 0.2f, 0.25f, 0.35f};
        float term_corr = sqrtf(expf(rt - 1.0f));
        float accl = 0.0f;
        #pragma unroll
        for (int l = 0; l < NL; ++l)
            accl += LW[l] * ts_s[tid][l] * sqrtf(expf(-mae_s[tid][l] * 0.01f));
        float sct = term_corr * accl;
        out[1 + tid] = sct;

        const float TW[TS] = {0.0075f, 0.02f, 0.03f, 0.04f, 0.05f, 0.06f, 0.07f,
                              0.08f, 0.09f, 0.1f, 0.09f, 0.08f, 0.07f, 0.06f,
                              0.05f, 0.04f, 0.03f, 0.02f, 0.0075f, 0.005f};
        sc_s[tid] = sct * TW[tid];
    }
    __syncthreads();

    if (tid == 0) {
        float tot = 0.0f;
        for (int t = 0; t < TS; ++t) tot += sc_s[t];
        out[0] = tot;
    }
    if (tid < NL) {
        float a = 0.0f, b = 0.0f;
        for (int t = 0; t < TS; ++t) { a += ts_s[t][tid]; b += mae_s[t][tid]; }
        out[241 + tid] = a * (1.0f / TS);
        out[246 + tid] = b * (1.0f / TS);
    }
}

extern "C" void kernel_launch(void* const* d_in, const int* in_sizes, int n_in,
                              void* d_out, int out_size, void* d_ws, size_t ws_size,
                              hipStream_t stream) {
    (void)in_sizes; (void)n_in; (void)out_size; (void)ws_size;
    const float4* pred = (const float4*)d_in[0];
    const float4* targ = (const float4*)d_in[1];
    const float4* mask = (const float4*)d_in[2];
    float* out  = (float*)d_out;
    float* sums = (float*)d_ws;

    // workspace is poisoned 0xAA before every launch — zero the accumulators
    hipMemsetAsync(sums, 0, TS * NS * sizeof(float), stream);

    dim3 grid(32, TS, 2);   // 1280 blocks: x = slab chunk, y = timestep, z = batch
    metscore_pass1<<<grid, 256, 0, stream>>>(pred, targ, mask, sums);
    metscore_final<<<1, 128, 0, stream>>>(sums, out);
}